// Round 2
// baseline (416.851 us; speedup 1.0000x reference)
//
#include <hip/hip_runtime.h>
#include <hip/hip_bf16.h>
#include <stdint.h>

#define B_   4
#define T_   2048
#define D_   1024
#define H_   16
#define HD_  64
#define MROWS (B_*T_)      // 8192
#define NQKV  3072

typedef __attribute__((ext_vector_type(8))) short  short8;   // 8 x bf16 = 4 VGPRs
typedef __attribute__((ext_vector_type(4))) float  floatx4;

#define QSCALE 0.1803368801111244f   // log2(e)/sqrt(64)

__device__ inline void async_copy16(const __hip_bfloat16* g, __hip_bfloat16* l) {
  __builtin_amdgcn_global_load_lds(
      (const __attribute__((address_space(1))) void*)g,
      (__attribute__((address_space(3))) void*)l, 16, 0, 0);
}

// ---------------- conversion kernels ----------------

__global__ void convert_bf16(const float* __restrict__ in, __hip_bfloat16* __restrict__ out, int n) {
  int i = (blockIdx.x * blockDim.x + threadIdx.x) * 4;
  if (i < n) {
    float4 v = *(const float4*)(in + i);
    out[i + 0] = __float2bfloat16(v.x);
    out[i + 1] = __float2bfloat16(v.y);
    out[i + 2] = __float2bfloat16(v.z);
    out[i + 3] = __float2bfloat16(v.w);
  }
}

// Wq/Wk/Wv [H][D][HD] fp32  ->  wqkv_bt [3072][1024] bf16, row n = which*1024 + h*64 + hd, col = d
__global__ void transpose_w(const float* __restrict__ Wq, const float* __restrict__ Wk,
                            const float* __restrict__ Wv, __hip_bfloat16* __restrict__ wqkv) {
  __shared__ __hip_bfloat16 tile[64][65];
  const int t = threadIdx.x;
  const int d0 = blockIdx.x * 64;      // 16 tiles over D
  const int wh = blockIdx.y;           // 0..47
  const int which = wh >> 4, h = wh & 15;
  const float* W = (which == 0) ? Wq : ((which == 1) ? Wk : Wv);
  const float* base = W + (size_t)h * D_ * HD_;
#pragma unroll
  for (int i = 0; i < 16; i++) {
    int e = i * 256 + t;
    int dr = e >> 6, hd = e & 63;
    tile[dr][hd] = __float2bfloat16(base[(size_t)(d0 + dr) * HD_ + hd]);
  }
  __syncthreads();
#pragma unroll
  for (int i = 0; i < 16; i++) {
    int e = i * 256 + t;
    int hd = e >> 6, dr = e & 63;
    wqkv[(size_t)(which * 1024 + h * 64 + hd) * D_ + d0 + dr] = tile[dr][hd];
  }
}

// v section of qkv [8192][3072] -> vt [B*H][HD][T]
__global__ void transpose_v(const __hip_bfloat16* __restrict__ qkv, __hip_bfloat16* __restrict__ vt) {
  __shared__ __hip_bfloat16 tile[64][65];
  const int t = threadIdx.x;
  const int bh = blockIdx.y, s0 = blockIdx.x * 64;
  const int b = bh >> 4, h = bh & 15;
#pragma unroll
  for (int i = 0; i < 16; i++) {
    int e = i * 256 + t;
    int s = e >> 6, hd = e & 63;
    tile[s][hd] = qkv[(size_t)(b * T_ + s0 + s) * NQKV + 2048 + h * HD_ + hd];
  }
  __syncthreads();
#pragma unroll
  for (int i = 0; i < 16; i++) {
    int e = i * 256 + t;
    int hd = e >> 6, s = e & 63;
    vt[((size_t)bh * 64 + hd) * T_ + s0 + s] = tile[s][hd];
  }
}

// ---------------- GEMM: C = A[M,K] * Bt[N,K]^T ----------------
// EPI==0: bf16 store with per-column scale (q columns scaled) -> Cb [M][N]
// EPI==1: fp32 store + bias -> Cf [M][N]
template <int EPI>
__launch_bounds__(256, 2)
__global__ void gemm_bt(const __hip_bfloat16* __restrict__ A, const __hip_bfloat16* __restrict__ Bt,
                        __hip_bfloat16* __restrict__ Cb, float* __restrict__ Cf,
                        const float* __restrict__ bias, int M, int N, int K, float qscale) {
  __shared__ __hip_bfloat16 As[128 * 32];
  __shared__ __hip_bfloat16 Bs[128 * 32];
  const int tid = threadIdx.x;
  const int w = tid >> 6, lane = tid & 63;
  const int lq = lane & 15, quad = lane >> 4;
  const int wr = w >> 1, wc = w & 1;
  const int m0 = blockIdx.x * 128, n0 = blockIdx.y * 128;

  floatx4 acc[4][4];
#pragma unroll
  for (int i = 0; i < 4; i++)
#pragma unroll
    for (int j = 0; j < 4; j++) acc[i][j] = (floatx4){0.f, 0.f, 0.f, 0.f};

  for (int k0 = 0; k0 < K; k0 += 32) {
    __syncthreads();
#pragma unroll
    for (int ph = 0; ph < 2; ++ph) {
      int c = ph * 256 + tid;          // chunk in [0,512): row = c>>2, col8 = c&3
      int row = c >> 2, col8 = c & 3;
      async_copy16(A + (size_t)(m0 + row) * K + k0 + col8 * 8, As + c * 8);
      async_copy16(Bt + (size_t)(n0 + row) * K + k0 + col8 * 8, Bs + c * 8);
    }
    __syncthreads();
    short8 af[4], bf[4];
#pragma unroll
    for (int mi = 0; mi < 4; mi++)
      af[mi] = *(const short8*)(As + (wr * 64 + mi * 16 + lq) * 32 + quad * 8);
#pragma unroll
    for (int ni = 0; ni < 4; ni++)
      bf[ni] = *(const short8*)(Bs + (wc * 64 + ni * 16 + lq) * 32 + quad * 8);
#pragma unroll
    for (int mi = 0; mi < 4; mi++)
#pragma unroll
      for (int ni = 0; ni < 4; ni++)
        acc[mi][ni] = __builtin_amdgcn_mfma_f32_16x16x32_bf16(af[mi], bf[ni], acc[mi][ni], 0, 0, 0);
  }

#pragma unroll
  for (int mi = 0; mi < 4; mi++) {
#pragma unroll
    for (int ni = 0; ni < 4; ni++) {
      int col = n0 + wc * 64 + ni * 16 + lq;
      if (EPI == 0) {
        float s = (col < 1024) ? qscale : 1.0f;
#pragma unroll
        for (int r = 0; r < 4; r++) {
          int row = m0 + wr * 64 + mi * 16 + quad * 4 + r;
          Cb[(size_t)row * N + col] = __float2bfloat16(acc[mi][ni][r] * s);
        }
      } else {
        float bv = bias[col];
#pragma unroll
        for (int r = 0; r < 4; r++) {
          int row = m0 + wr * 64 + mi * 16 + quad * 4 + r;
          Cf[(size_t)row * N + col] = acc[mi][ni][r] + bv;
        }
      }
    }
  }
}

// ---------------- flash attention ----------------
// qkv [8192][3072] bf16 (q scaled by log2e/8), vt [B*H][64][2048] bf16 -> obuf [8192][1024] bf16
__launch_bounds__(256, 2)
__global__ void attn(const __hip_bfloat16* __restrict__ qkv, const __hip_bfloat16* __restrict__ vt,
                     __hip_bfloat16* __restrict__ obuf) {
  __shared__ __hip_bfloat16 Ks[64][72];   // K[s][k]  (natural)
  __shared__ __hip_bfloat16 Vs[64][72];   // V^T[hd][s]
  __shared__ __hip_bfloat16 Ps[64][72];   // P[t_local][s]  (wave-private 16-row bands)

  const int tid = threadIdx.x;
  const int w = tid >> 6, lane = tid & 63;
  const int lq = lane & 15, quad = lane >> 4;
  const int bh = blockIdx.y;
  const int b = bh >> 4, h = bh & 15;
  const int qt0 = (int)(gridDim.x - 1 - blockIdx.x) * 64;  // heavy blocks first

  // Q fragments for this wave's 16 rows (k split in two halves of 32)
  // A-operand layout: A[m=lane&15][k=quad*8+j]  -> each quad loads its own k-slice
  short8 qf[2];
  {
    const size_t row = (size_t)(b * T_ + qt0 + w * 16 + lq);
    const __hip_bfloat16* qp = qkv + row * NQKV + h * HD_;
    qf[0] = *(const short8*)(qp + quad * 8);
    qf[1] = *(const short8*)(qp + 32 + quad * 8);
  }

  floatx4 Oacc[4];
#pragma unroll
  for (int i = 0; i < 4; i++) Oacc[i] = (floatx4){0.f, 0.f, 0.f, 0.f};
  float mrow[4], lrow[4];
#pragma unroll
  for (int r = 0; r < 4; r++) { mrow[r] = -__builtin_inff(); lrow[r] = 0.f; }

  const int nIter = qt0 / 64 + 1;
  for (int it = 0; it < nIter; ++it) {
    const int s0 = it * 64;
    __syncthreads();
    // stage K tile (natural) and V^T tile from pre-transposed vt
#pragma unroll
    for (int ph = 0; ph < 2; ++ph) {
      int c = ph * 256 + tid;       // [0,512): row=c>>3, col8=c&7
      int row = c >> 3, col8 = c & 7;
      *(uint4*)&Ks[row][col8 * 8] =
          *(const uint4*)(qkv + (size_t)(b * T_ + s0 + row) * NQKV + 1024 + h * HD_ + col8 * 8);
      *(uint4*)&Vs[row][col8 * 8] =
          *(const uint4*)(vt + ((size_t)bh * 64 + row) * T_ + s0 + col8 * 8);
    }
    __syncthreads();

    // S = Q K^T  (already in exp2 domain: scale folded into q)
    floatx4 Sc[4];
#pragma unroll
    for (int ni = 0; ni < 4; ni++) {
      short8 kf0 = *(const short8*)&Ks[ni * 16 + lq][quad * 8];
      short8 kf1 = *(const short8*)&Ks[ni * 16 + lq][32 + quad * 8];
      floatx4 c0 = (floatx4){0.f, 0.f, 0.f, 0.f};
      c0 = __builtin_amdgcn_mfma_f32_16x16x32_bf16(qf[0], kf0, c0, 0, 0, 0);
      c0 = __builtin_amdgcn_mfma_f32_16x16x32_bf16(qf[1], kf1, c0, 0, 0, 0);
      Sc[ni] = c0;
    }

    // causal mask on diagonal tile only
    if (s0 == qt0) {
#pragma unroll
      for (int ni = 0; ni < 4; ni++)
#pragma unroll
        for (int r = 0; r < 4; r++) {
          int scol = ni * 16 + lq;
          int trow = w * 16 + quad * 4 + r;
          if (scol > trow) Sc[ni][r] = -__builtin_inff();
        }
    }

    // online softmax (base-2 domain). C layout: col=lq, row=quad*4+r
    float alpha[4];
#pragma unroll
    for (int r = 0; r < 4; r++) {
      float rm = fmaxf(fmaxf(Sc[0][r], Sc[1][r]), fmaxf(Sc[2][r], Sc[3][r]));
      rm = fmaxf(rm, __shfl_xor(rm, 1));
      rm = fmaxf(rm, __shfl_xor(rm, 2));
      rm = fmaxf(rm, __shfl_xor(rm, 4));
      rm = fmaxf(rm, __shfl_xor(rm, 8));
      float mn = fmaxf(mrow[r], rm);
      alpha[r] = __builtin_amdgcn_exp2f(mrow[r] - mn);
      mrow[r] = mn;
    }
    float psum[4] = {0.f, 0.f, 0.f, 0.f};
#pragma unroll
    for (int ni = 0; ni < 4; ni++)
#pragma unroll
      for (int r = 0; r < 4; r++) {
        float p = __builtin_amdgcn_exp2f(Sc[ni][r] - mrow[r]);
        Sc[ni][r] = p;
        psum[r] += p;
      }
#pragma unroll
    for (int r = 0; r < 4; r++) {
      float ps = psum[r];
      ps += __shfl_xor(ps, 1);
      ps += __shfl_xor(ps, 2);
      ps += __shfl_xor(ps, 4);
      ps += __shfl_xor(ps, 8);
      lrow[r] = lrow[r] * alpha[r] + ps;
#pragma unroll
      for (int nt = 0; nt < 4; nt++) Oacc[nt][r] *= alpha[r];
    }

    // P: C-layout regs -> LDS (A-layout source for PV)
#pragma unroll
    for (int ni = 0; ni < 4; ni++)
#pragma unroll
      for (int r = 0; r < 4; r++)
        Ps[w * 16 + quad * 4 + r][ni * 16 + lq] = __float2bfloat16(Sc[ni][r]);
    __syncthreads();

    // O += P V
#pragma unroll
    for (int kk = 0; kk < 2; kk++) {
      short8 pf = *(const short8*)&Ps[w * 16 + lq][kk * 32 + quad * 8];
#pragma unroll
      for (int nt = 0; nt < 4; nt++) {
        short8 vf = *(const short8*)&Vs[nt * 16 + lq][kk * 32 + quad * 8];
        Oacc[nt] = __builtin_amdgcn_mfma_f32_16x16x32_bf16(pf, vf, Oacc[nt], 0, 0, 0);
      }
    }
  }

  // epilogue: O / l  -> obuf [B,T,H*HD]
#pragma unroll
  for (int r = 0; r < 4; r++) {
    float inv = 1.0f / lrow[r];
    int t = qt0 + w * 16 + quad * 4 + r;
#pragma unroll
    for (int nt = 0; nt < 4; nt++)
      obuf[(size_t)(b * T_ + t) * D_ + h * HD_ + nt * 16 + lq] =
          __float2bfloat16(Oacc[nt][r] * inv);
  }
}

// ---------------- launch ----------------

extern "C" void kernel_launch(void* const* d_in, const int* in_sizes, int n_in,
                              void* d_out, int out_size, void* d_ws, size_t ws_size,
                              hipStream_t stream) {
  const float* x  = (const float*)d_in[0];
  const float* Wq = (const float*)d_in[1];
  const float* Wk = (const float*)d_in[2];
  const float* Wv = (const float*)d_in[3];
  const float* Wo = (const float*)d_in[4];
  const float* bo = (const float*)d_in[5];
  float* out = (float*)d_out;

  char* ws = (char*)d_ws;
  __hip_bfloat16* xb   = (__hip_bfloat16*)(ws);                          // 16 MB
  __hip_bfloat16* wqkv = (__hip_bfloat16*)(ws + ((size_t)16 << 20));     //  6 MB
  __hip_bfloat16* wob  = (__hip_bfloat16*)(ws + ((size_t)22 << 20));     //  2 MB
  __hip_bfloat16* qkv  = (__hip_bfloat16*)(ws + ((size_t)24 << 20));     // 48 MB
  __hip_bfloat16* vt   = (__hip_bfloat16*)(ws + ((size_t)72 << 20));     // 16 MB
  __hip_bfloat16* obuf = (__hip_bfloat16*)(ws + ((size_t)88 << 20));     // 16 MB

  convert_bf16<<<(MROWS * D_) / 1024, 256, 0, stream>>>(x, xb, MROWS * D_);
  convert_bf16<<<(D_ * D_) / 1024, 256, 0, stream>>>(Wo, wob, D_ * D_);
  transpose_w<<<dim3(16, 48), 256, 0, stream>>>(Wq, Wk, Wv, wqkv);

  // qkv = xb * wqkv^T   (q columns pre-scaled by log2e/8)
  gemm_bt<0><<<dim3(MROWS / 128, NQKV / 128), 256, 0, stream>>>(
      xb, wqkv, qkv, nullptr, nullptr, MROWS, NQKV, D_, QSCALE);

  transpose_v<<<dim3(T_ / 64, B_ * H_), 256, 0, stream>>>(qkv, vt);

  attn<<<dim3(T_ / 64, B_ * H_), 256, 0, stream>>>(qkv, vt, obuf);

  // out = obuf * Wo^T + bo
  gemm_bt<1><<<dim3(MROWS / 128, D_ / 128), 256, 0, stream>>>(
      obuf, wob, nullptr, out, bo, MROWS, D_, D_, 1.0f);
}